// Round 1
// baseline (217.266 us; speedup 1.0000x reference)
//
#include <hip/hip_runtime.h>
#include <stdint.h>

// Problem: x (32,128,8192) f32, weight (128,128,1,2) f32
// out[b,o,p] = sum_{c,k} x[b,c,2p+k] * w[o,c,k] / sqrt(128),  out (32,128,4096) f32
// GEMM: M=(b,p)=131072, N=o=128, K=(c,k)=256. Memory-bound with bf16 MFMA.
//
// R3: single-kernel version. Weight f32->bf16 conversion (scale folded, RTNE,
// bit-identical to old convert_w) moved into a per-block LDS prologue (64 KB,
// B-fragment-major). Main-loop B reads become ds_read_b128 on the lgkmcnt
// path, so the vmcnt queue carries ONLY the distance-1 A prefetch (in-order
// vmcnt previously forced B waits to drain the A prefetch). Blocks are 512
// threads (8 waves, 256 positions) so 2 blocks/CU keeps 16 waves/CU with the
// 64 KB LDS. Kills the convert_w dispatch + gap and all workspace use.

typedef __attribute__((ext_vector_type(8))) short bf16x8;   // 8 bf16 = 4 VGPRs
typedef __attribute__((ext_vector_type(4))) float f32x4;    // MFMA C/D

#define CIN  128
#define DLEN 8192
#define PLEN 4096
#define COUT 128

__device__ inline unsigned short f2bf(float f) {
    unsigned u = __builtin_bit_cast(unsigned, f);
    unsigned r = u + 0x7FFFu + ((u >> 16) & 1u);
    return (unsigned short)(r >> 16);
}

// pack two fp32 -> bf16x2 (RTNE), lo = a, hi = b
__device__ inline unsigned pack_bf(float a, float b) {
    unsigned ua = __builtin_bit_cast(unsigned, a);
    unsigned ub = __builtin_bit_cast(unsigned, b);
    unsigned ra = ua + 0x7FFFu + ((ua >> 16) & 1u);
    unsigned rb = ub + 0x7FFFu + ((ub >> 16) & 1u);
    return (ra >> 16) | (rb & 0xFFFF0000u);
}

// One block = 8 waves = 512 threads, covers 256 positions of one batch, all
// 128 outputs, K=256. Each wave: 32 consecutive positions, interleaved across
// two 16x16 M-tiles (tile0 = even offsets, tile1 = odd), so each A row load is
// one float4 covering both tiles. B (weights) staged once per block into LDS
// in fragment-major bf16 layout: bf16 idx = (kk>>3)*1024 + o*8 + (kk&7).
__global__ __launch_bounds__(512, 4) void conv_mfma(const float* __restrict__ x,
                                                    const float* __restrict__ wsrc,
                                                    float* __restrict__ out) {
    __shared__ unsigned wlds[16384];   // 64 KB: dword idx = (kk>>3)*512 + o*4 + ((kk&7)>>1)

    // ---- prologue: convert weights f32 -> bf16 into LDS, scale folded ----
    const float scale = 0.088388347648318447f; // 1/sqrt(128)
#pragma unroll 4
    for (int t = threadIdx.x; t < 4096; t += 512) {
        int o  = t >> 5;                 // 0..127
        int k0 = (t & 31) * 8;           // 0..248 step 8
        const float* wp = wsrc + o * 256 + k0;
        float4 f0 = *(const float4*)(wp);
        float4 f1 = *(const float4*)(wp + 4);
        uint4 v;
        v.x = pack_bf(f0.x * scale, f0.y * scale);
        v.y = pack_bf(f0.z * scale, f0.w * scale);
        v.z = pack_bf(f1.x * scale, f1.y * scale);
        v.w = pack_bf(f1.z * scale, f1.w * scale);
        *(uint4*)&wlds[(k0 >> 3) * 512 + o * 4] = v;
    }
    __syncthreads();

    int tile = blockIdx.x;            // 0..511
    int b    = tile >> 4;             // 0..31
    int pt   = (tile & 15) * 256;     // position base of block
    int lane = threadIdx.x & 63;
    int w    = threadIdx.x >> 6;      // wave 0..7
    int quad = lane >> 4;
    int l16  = lane & 15;
    int pbase = pt + w * 32;          // wave's 32-position strip

    // A lane base: row c = quad*4 (+jj, +16*kc), elem 2*pbase + 4*l16
    const float* xl = x + (size_t)b * ((size_t)CIN * DLEN)
                        + (size_t)(quad * 4) * DLEN + 2 * pbase + 4 * l16;
    const unsigned* bb = wlds + quad * 512 + l16 * 4;

    f32x4 acc[2][8];
#pragma unroll
    for (int mt = 0; mt < 2; ++mt)
#pragma unroll
        for (int t = 0; t < 8; ++t)
            acc[mt][t] = (f32x4)(0.0f);

    // preload kc=0 A
    float4 abuf[4];
#pragma unroll
    for (int jj = 0; jj < 4; ++jj)
        abuf[jj] = *(const float4*)(xl + (size_t)jj * DLEN);

#pragma unroll 1
    for (int kc = 0; kc < 8; ++kc) {
        // consume current A: .x/.y -> tile0 (even pos), .z/.w -> tile1 (odd pos)
        union { bf16x8 v; unsigned uu[4]; } afr0, afr1;
#pragma unroll
        for (int jj = 0; jj < 4; ++jj) {
            afr0.uu[jj] = pack_bf(abuf[jj].x, abuf[jj].y);
            afr1.uu[jj] = pack_bf(abuf[jj].z, abuf[jj].w);
        }
        // prefetch next kc A (distance 1, same regs — abuf already consumed)
        if (kc < 7) {
            const float* nx = xl + (size_t)((kc + 1) * 16) * DLEN;
#pragma unroll
            for (int jj = 0; jj < 4; ++jj)
                abuf[jj] = *(const float4*)(nx + (size_t)jj * DLEN);
        }
        // B fragments for this kc from LDS: kgroup = kc*4+quad, t-stride 64 dwords
        const unsigned* bk = bb + kc * 2048;
#pragma unroll
        for (int th = 0; th < 2; ++th) {
            union { bf16x8 v; uint4 u; } bfr[4];
#pragma unroll
            for (int tt = 0; tt < 4; ++tt)
                bfr[tt].u = *(const uint4*)(bk + (th * 4 + tt) * 64);
#pragma unroll
            for (int tt = 0; tt < 4; ++tt) {
                int t = th * 4 + tt;
                acc[0][t] = __builtin_amdgcn_mfma_f32_16x16x32_bf16(afr0.v, bfr[tt].v, acc[0][t], 0, 0, 0);
                acc[1][t] = __builtin_amdgcn_mfma_f32_16x16x32_bf16(afr1.v, bfr[tt].v, acc[1][t], 0, 0, 0);
            }
        }
    }

    // Epilogue: C/D row = quad*4 + reg. tile0 reg r -> p = pbase+8q+2r,
    // tile1 -> +1. Interleave regs -> 8 consecutive positions per t.
    float* ob = out + (size_t)b * ((size_t)COUT * PLEN) + pbase + quad * 8;
#pragma unroll
    for (int t = 0; t < 8; ++t) {
        int o = t * 16 + l16;
        float* orow = ob + (size_t)o * PLEN;
        f32x4 v0 = { acc[0][t][0], acc[1][t][0], acc[0][t][1], acc[1][t][1] };
        f32x4 v1 = { acc[0][t][2], acc[1][t][2], acc[0][t][3], acc[1][t][3] };
        *(f32x4*)(orow)     = v0;
        *(f32x4*)(orow + 4) = v1;
    }
}

extern "C" void kernel_launch(void* const* d_in, const int* in_sizes, int n_in,
                              void* d_out, int out_size, void* d_ws, size_t ws_size,
                              hipStream_t stream) {
    const float* x = (const float*)d_in[0];
    const float* w = (const float*)d_in[1];
    float* out = (float*)d_out;
    (void)d_ws; (void)ws_size;

    conv_mfma<<<512, 512, 0, stream>>>(x, w, out);
}